// Round 3
// baseline (505.813 us; speedup 1.0000x reference)
//
#include <hip/hip_runtime.h>

typedef unsigned short u16;
typedef __bf16 bf16x8 __attribute__((ext_vector_type(8)));
typedef float f32x4 __attribute__((ext_vector_type(4)));

#define SCALE_QK 0.08838834764831845f
#define LOG2E 1.4426950408889634f
#define NEGBIG (-1e9f)

static __device__ __forceinline__ float bf2f(u16 u) {
  union { float f; unsigned int i; } x; x.i = ((unsigned int)u) << 16; return x.f;
}
static __device__ __forceinline__ u16 f2bf(float f) {
  union { float f; unsigned int i; } x; x.f = f;
  return (u16)((x.i + 0x7fffu + ((x.i >> 16) & 1u)) >> 16);
}
static __device__ __forceinline__ void async16(const u16* g, u16* s) {
  __builtin_amdgcn_global_load_lds(
      (const __attribute__((address_space(1))) void*)g,
      (__attribute__((address_space(3))) void*)s, 16, 0, 0);
}

// -------- dtype probe: flags[t]=1 if tensor t is f32-stored, 0 if bf16 ------
__global__ __launch_bounds__(64) void detect_dtype(
    const void* p0, const void* p1, const void* p2, const void* p3,
    const void* p4, const void* p5, int* flags) {
  const void* ps[6] = {p0, p1, p2, p3, p4, p5};
  const u16* p = (const u16*)ps[blockIdx.x];
  int lane = threadIdx.x;
  u16 u = p[2 * lane];
  int e = (u >> 7) & 0xFF;
  int plaus = (e >= 112 && e <= 143) ? 1 : 0;
  unsigned long long m = __ballot(plaus);
  if (lane == 0) {
    flags[blockIdx.x] = (__popcll(m) < 32) ? 1 : 0;
    if (blockIdx.x == 0) flags[6] = 0;  // forced-bf16 flag (internal GEMM out)
  }
}

// -------- shared transpose body: src (K x N) tile -> dst bf16 (N x K) -------
static __device__ __forceinline__ void transpose_body(
    const void* __restrict__ src, u16* __restrict__ dst, int N, int K,
    int n0, int k0, int f32in, u16* t) {
  const int LT = 74;
  const int tid = threadIdx.x;
  for (int c = tid; c < 512; c += 256) {
    int r = c >> 3, ch = (c & 7) * 8;
    u16* tp = t + r * LT + ch;
    if (f32in) {
      const float* p = (const float*)src + (size_t)(k0 + r) * N + n0 + ch;
      float4 v0 = *(const float4*)p;
      float4 v1 = *(const float4*)(p + 4);
      tp[0] = f2bf(v0.x); tp[1] = f2bf(v0.y); tp[2] = f2bf(v0.z); tp[3] = f2bf(v0.w);
      tp[4] = f2bf(v1.x); tp[5] = f2bf(v1.y); tp[6] = f2bf(v1.z); tp[7] = f2bf(v1.w);
    } else {
      uint4 v = *(const uint4*)((const u16*)src + (size_t)(k0 + r) * N + n0 + ch);
      const u16* pv = (const u16*)&v;
#pragma unroll
      for (int e = 0; e < 8; ++e) tp[e] = pv[e];
    }
  }
  __syncthreads();
  for (int c = tid; c < 512; c += 256) {
    int rr = c >> 3, cc = (c & 7) * 8;
    u16 tmp[8];
#pragma unroll
    for (int e = 0; e < 8; ++e) tmp[e] = t[(cc + e) * LT + rr];
    *(uint4*)(dst + (size_t)(n0 + rr) * K + k0 + cc) = *(const uint4*)tmp;
  }
}

// -------- transpose: generic single-tensor version (used for Wo) ------------
__global__ __launch_bounds__(256) void transpose_to_bf16(
    const void* __restrict__ src, u16* __restrict__ dst, int N, int K,
    const int* __restrict__ flag) {
  __shared__ u16 t[64 * 74];
  transpose_body(src, dst, N, K, blockIdx.x * 64, blockIdx.y * 64, *flag, t);
}

// -------- fused transpose of Wq/Wk/Wv into Wqkvt (one launch) ---------------
__global__ __launch_bounds__(256) void transpose_qkv(
    const void* __restrict__ Wq, const void* __restrict__ Wk,
    const void* __restrict__ Wv, u16* __restrict__ dst,
    const int* __restrict__ flags) {
  __shared__ u16 t[64 * 74];
  int bx = blockIdx.x;
  const void* src; u16* d; int N; int f32in; int nx;
  if (bx < 64)      { src = Wq; d = dst;                         N = 4096; f32in = flags[2]; nx = bx; }
  else if (bx < 80) { src = Wk; d = dst + (size_t)4096 * 4096;   N = 1024; f32in = flags[3]; nx = bx - 64; }
  else              { src = Wv; d = dst + (size_t)5120 * 4096;   N = 1024; f32in = flags[4]; nx = bx - 80; }
  transpose_body(src, d, N, 4096, nx * 64, blockIdx.y * 64, f32in, t);
}

// -------- flat cast to bf16 -------------------------------------------------
__global__ __launch_bounds__(256) void cast_to_bf16(
    const void* __restrict__ src, u16* __restrict__ dst, const int* __restrict__ flag) {
  int i = (blockIdx.x * 256 + threadIdx.x) * 8;
  if (*flag) {
    float4 v0 = *(const float4*)((const float*)src + i);
    float4 v1 = *(const float4*)((const float*)src + i + 4);
    u16 tmp[8] = {f2bf(v0.x), f2bf(v0.y), f2bf(v0.z), f2bf(v0.w),
                  f2bf(v1.x), f2bf(v1.y), f2bf(v1.z), f2bf(v1.w)};
    *(uint4*)(dst + i) = *(const uint4*)tmp;
  } else {
    *(uint4*)(dst + i) = *(const uint4*)((const u16*)src + i);
  }
}

// -------- phased GEMM: C(MxN) = A(MxK)*Bt(NxK)^T ---------------------------
// 256-class dbuf template (T1 XCD swizzle + T2 chunk-XOR swizzle + T3/T4
// phased schedule w/ boundary-only vmcnt + T5 setprio). 512 thr = 8 waves
// (NWM x NWN), BK=64, 4 phases/K-tile (one C-quadrant x K=64 each).
// Sync design:
//  - stages (global_load_lds) in iter t target buf (t+1)&1; reads hit buf
//    t&1 only -> no intra-iteration alias.
//  - each phase: ds_read -> raw s_barrier -> lgkmcnt(0)+sched_barrier ->
//    MFMA (setprio 1) -> raw s_barrier. lgkmcnt(0) before MFMA means every
//    wave's LDS reads are DONE before its last-phase barrier, so next
//    iteration's stage writes (issued after that barrier) cannot overtake.
//  - one vmcnt(0) per K-tile at phase 3 (+barrier): own stage loads done;
//    barrier makes that true for all waves. Loads stay in flight across all
//    intra-iteration barriers (never drained mid-tile).
// T2 swizzle: LDS dest is linear (gload_lds requirement); the involution
// chunk ^= (row&7) on 16B chunks is applied to the per-lane GLOBAL source
// and identically on the ds_read address (both-sides, rule 21).
template <int BM, int BN, int NWM, int NWN>
__global__ __launch_bounds__(512, 2) void gemm_ph(
    const u16* __restrict__ A, const u16* __restrict__ Bt, void* __restrict__ C,
    int K, int lda, int ldb, int ldc, const int* __restrict__ oflag) {
  constexpr int LA = BM / 64, LB = BN / 64, L = LA + LB;  // stage loads/thread
  constexpr int WM = BM / NWM, WN = BN / NWN;
  constexpr int FM = WM / 16, FN = WN / 16;
  constexpr int BUF = (BM + BN) * 64;  // elems per dbuf half
  __shared__ u16 lds[BUF * 2];
  const int tid = threadIdx.x;
  const int wave = tid >> 6, lane = tid & 63;
  const int quad = lane >> 4, l16 = lane & 15;
  const int wr = wave / NWN, wc = wave % NWN;

  // XCD-contiguous swizzle (grids are multiples of 8): each XCD gets a
  // contiguous run of logical ids = one full row-panel -> A-panel L2-resident.
  const int nwg = gridDim.x * gridDim.y;
  const int flat = blockIdx.y * gridDim.x + blockIdx.x;
  const int swz = (flat & 7) * (nwg >> 3) + (flat >> 3);
  const int bm = (swz / gridDim.x) * BM;
  const int bn = (swz % gridDim.x) * BN;
  const int f32out = *oflag;

  // staging source (pre-swizzled 16B chunks within each 128B row-segment)
  const int srow = tid >> 3;                      // 0..63
  const int scol = ((tid & 7) ^ (srow & 7)) * 8;  // swizzled k-chunk
  const u16* gA = A + (size_t)(bm + srow) * lda + scol;
  const u16* gB = Bt + (size_t)(bn + srow) * ldb + scol;

  f32x4 acc[FM][FN] = {};
  const int nk = K >> 6;

  // prologue: stage K-tile 0 into buf 0
#pragma unroll
  for (int i = 0; i < LA; ++i)
    async16(gA + (size_t)(i * 64) * lda, lds + i * 4096 + tid * 8);
#pragma unroll
  for (int j = 0; j < LB; ++j)
    async16(gB + (size_t)(j * 64) * ldb, lds + BM * 64 + j * 4096 + tid * 8);
  __asm__ __volatile__("s_waitcnt vmcnt(0)" ::: "memory");
  __asm__ __volatile__("s_barrier" ::: "memory");

  // ds_read chunk offsets (elems): kstep 0/1, involution-swizzled
  const int ch0 = (quad ^ (l16 & 7)) * 8;
  const int ch1 = ((4 + quad) ^ (l16 & 7)) * 8;

  for (int t = 0; t < nk; ++t) {
    const u16* bufA = lds + (t & 1) * BUF;
    const u16* bufB = bufA + BM * 64;
    u16* nbuf = lds + ((t + 1) & 1) * BUF;
    const int kn = (t + 1) << 6;
    const bool more = (t + 1) < nk;

    bf16x8 af[FM / 2][2];  // current A half (overwritten at ph2)
    bf16x8 bv[FN][2];      // all B frags, resident for the K-tile
#pragma unroll
    for (int ph = 0; ph < 4; ++ph) {
      const int mh = ph >> 1, nh = ph & 1;
      // ds_reads: ph0: A-half0 + B-half0; ph1: B-half1; ph2: A-half1
      if (ph == 0 || ph == 2) {
#pragma unroll
        for (int mi = 0; mi < FM / 2; ++mi) {
          const u16* p = bufA + (wr * WM + (mh * (FM / 2) + mi) * 16 + l16) * 64;
          af[mi][0] = *(const bf16x8*)(p + ch0);
          af[mi][1] = *(const bf16x8*)(p + ch1);
        }
      }
      if (ph < 2) {
#pragma unroll
        for (int ni = 0; ni < FN / 2; ++ni) {
          const int n = ph * (FN / 2) + ni;
          const u16* p = bufB + (wc * WN + n * 16 + l16) * 64;
          bv[n][0] = *(const bf16x8*)(p + ch0);
          bv[n][1] = *(const bf16x8*)(p + ch1);
        }
      }
      // stage slice for next K-tile (2-ish loads/phase, other buffer)
      if (more) {
#pragma unroll
        for (int i = 0; i < LA; ++i)
          if (i >= ph * L / 4 && i < (ph + 1) * L / 4)
            async16(gA + (size_t)(i * 64) * lda + kn, nbuf + i * 4096 + tid * 8);
#pragma unroll
        for (int j = 0; j < LB; ++j)
          if (LA + j >= ph * L / 4 && LA + j < (ph + 1) * L / 4)
            async16(gB + (size_t)(j * 64) * ldb + kn,
                    nbuf + BM * 64 + j * 4096 + tid * 8);
      }
      __asm__ __volatile__("s_barrier" ::: "memory");
      __asm__ __volatile__("s_waitcnt lgkmcnt(0)" ::: "memory");
      __builtin_amdgcn_sched_barrier(0);
      __builtin_amdgcn_s_setprio(1);
#pragma unroll
      for (int mi = 0; mi < FM / 2; ++mi)
#pragma unroll
        for (int ni = 0; ni < FN / 2; ++ni) {
          const int cm = mh * (FM / 2) + mi, cn = nh * (FN / 2) + ni;
          acc[cm][cn] = __builtin_amdgcn_mfma_f32_16x16x32_bf16(
              af[mi][0], bv[cn][0], acc[cm][cn], 0, 0, 0);
          acc[cm][cn] = __builtin_amdgcn_mfma_f32_16x16x32_bf16(
              af[mi][1], bv[cn][1], acc[cm][cn], 0, 0, 0);
        }
      __builtin_amdgcn_s_setprio(0);
      if (ph == 3) __asm__ __volatile__("s_waitcnt vmcnt(0)" ::: "memory");
      __asm__ __volatile__("s_barrier" ::: "memory");
    }
  }

  // epilogue (C/D layout: row = m*16 + quad*4 + r, col = n*16 + l16)
#pragma unroll
  for (int mi = 0; mi < FM; ++mi) {
    int row = bm + wr * WM + mi * 16 + quad * 4;
#pragma unroll
    for (int ni = 0; ni < FN; ++ni) {
      int col = bn + wc * WN + ni * 16 + l16;
#pragma unroll
      for (int r = 0; r < 4; ++r) {
        size_t idx = (size_t)(row + r) * ldc + col;
        if (f32out) ((float*)C)[idx] = acc[mi][ni][r];
        else ((u16*)C)[idx] = f2bf(acc[mi][ni][r]);
      }
    }
  }
}

// -------- RoPE in place, vectorized x8: Q (slots 0..31), K (slots 32..39) ---
__global__ __launch_bounds__(256) void rope_kernel(
    u16* __restrict__ QKV, const void* __restrict__ cosb,
    const void* __restrict__ sinb, const int* __restrict__ flag) {
  int idx = blockIdx.x * 256 + threadIdx.x;  // (tok*40 + slot)*8 + d-octet
  int d8 = (idx & 7) * 8;
  int rest = idx >> 3;
  int slot = rest % 40;
  int tok = rest / 40;
  int col = (slot < 32) ? (slot * 128 + d8) : (4096 + (slot - 32) * 128 + d8);
  size_t base = (size_t)tok * 6144 + col;
  uint4 va = *(const uint4*)(QKV + base);        // x1: d8..d8+7
  uint4 vb = *(const uint4*)(QKV + base + 64);   // x2: d8+64..d8+71
  const u16* pa = (const u16*)&va;
  const u16* pb = (const u16*)&vb;
  size_t cb = (size_t)tok * 128 + d8;
  float c1[8], s1[8], c2[8], s2[8];
  if (*flag) {
    const float* cp = (const float*)cosb + cb;
    const float* sp = (const float*)sinb + cb;
    float4 t0 = *(const float4*)cp,        t1 = *(const float4*)(cp + 4);
    float4 t2 = *(const float4*)(cp + 64), t3 = *(const float4*)(cp + 68);
    float4 u0 = *(const float4*)sp,        u1 = *(const float4*)(sp + 4);
    float4 u2 = *(const float4*)(sp + 64), u3 = *(const float4*)(sp + 68);
    c1[0]=t0.x;c1[1]=t0.y;c1[2]=t0.z;c1[3]=t0.w;c1[4]=t1.x;c1[5]=t1.y;c1[6]=t1.z;c1[7]=t1.w;
    c2[0]=t2.x;c2[1]=t2.y;c2[2]=t2.z;c2[3]=t2.w;c2[4]=t3.x;c2[5]=t3.y;c2[6]=t3.z;c2[7]=t3.w;
    s1[0]=u0.x;s1[1]=u0.y;s1[2]=u0.z;s1[3]=u0.w;s1[4]=u1.x;s1[5]=u1.y;s1[6]=u1.z;s1[7]=u1.w;
    s2[0]=u2.x;s2[1]=u2.y;s2[2]=u2.z;s2[3]=u2.w;s2[4]=u3.x;s2[5]=u3.y;s2[6]=u3.z;s2[7]=u3.w;
  } else {
    const u16* cp = (const u16*)cosb + cb;
    const u16* sp = (const u16*)sinb + cb;
    uint4 t0 = *(const uint4*)cp, t1 = *(const uint4*)(cp + 64);
    uint4 u0 = *(const uint4*)sp, u1 = *(const uint4*)(sp + 64);
    const u16* q0 = (const u16*)&t0; const u16* q1 = (const u16*)&t1;
    const u16* r0 = (const u16*)&u0; const u16* r1 = (const u16*)&u1;
#pragma unroll
    for (int e = 0; e < 8; ++e) {
      c1[e] = bf2f(q0[e]); c2[e] = bf2f(q1[e]);
      s1[e] = bf2f(r0[e]); s2[e] = bf2f(r1[e]);
    }
  }
  u16 o1[8], o2[8];
#pragma unroll
  for (int e = 0; e < 8; ++e) {
    float x1 = bf2f(pa[e]), x2 = bf2f(pb[e]);
    o1[e] = f2bf(x1 * c1[e] - x2 * s1[e]);
    o2[e] = f2bf(x2 * c2[e] + x1 * s2[e]);
  }
  *(uint4*)(QKV + base) = *(const uint4*)o1;
  *(uint4*)(QKV + base + 64) = *(const uint4*)o2;
}

// -------- flash attention: BQ=BKV=64, causal, GQA 4:1 -----------------------
// Swapped QK^T (mfma(K,Q) -> S^T), per-lane in-register softmax, defer-max
// (THR=8, log2 domain), sP transposed round-trip, sV XOR-swizzled
// transpose-store, K/V next-tile reg prefetch, paired q-tiles {p,15-p}.
__global__ __launch_bounds__(256, 3) void attn_kernel(
    const u16* __restrict__ QKV, u16* __restrict__ O) {
  const int LK = 136;
  const int LP = 72;
  __shared__ u16 sK[64 * LK];
  __shared__ u16 sV[128 * 64];
  __shared__ u16 sP[64 * LP];
  const int tid = threadIdx.x, wave = tid >> 6, lane = tid & 63;
  const int quad = lane >> 4, l16 = lane & 15;
  const int pp = blockIdx.x, h = blockIdx.y, b = blockIdx.z;
  const int kvh = h >> 2;
  const size_t tb = (size_t)b * 1024 * 6144;
  const u16* Qg = QKV + tb + (size_t)h * 128;
  const u16* Kg = QKV + tb + 4096 + (size_t)kvh * 128;
  const u16* Vg = QKV + tb + 5120 + (size_t)kvh * 128;

#pragma unroll 1
  for (int pass = 0; pass < 2; ++pass) {
    const int qt = pass ? (15 - pp) : pp;

    bf16x8 qa[4];
    {
      const int qrow = qt * 64 + wave * 16 + l16;
#pragma unroll
      for (int kc = 0; kc < 4; ++kc) {
        bf16x8 v = *(const bf16x8*)(Qg + (size_t)qrow * 6144 + kc * 32 + quad * 8);
#pragma unroll
        for (int e = 0; e < 8; ++e) v[e] = (__bf16)((float)v[e] * (SCALE_QK * LOG2E));
        qa[kc] = v;
      }
    }

    uint4 kreg[4], vreg[4];
#pragma unroll
    for (int i = 0; i < 4; ++i) {
      int c = i * 256 + tid, row = c >> 4, ch = (c & 15) * 8;
      kreg[i] = *(const uint4*)(Kg + (size_t)row * 6144 + ch);
      vreg[i] = *(const uint4*)(Vg + (size_t)row * 6144 + ch);
    }

    float m_run = -INFINITY, l_run = 0.f;
    f32x4 oacc[8] = {};
    const int qg = qt * 64 + wave * 16 + l16;

    const int nkb = qt + 1;
    for (int kb = 0; kb < nkb; ++kb) {
#pragma unroll
      for (int i = 0; i < 4; ++i) {
        int c = i * 256 + tid, row = c >> 4, ch = (c & 15) * 8;
        *(uint4*)(sK + row * LK + ch) = kreg[i];
        const u16* pw = (const u16*)&vreg[i];
#pragma unroll
        for (int e = 0; e < 8; ++e) {
          int d = ch + e;
          sV[d * 64 + ((((row >> 3) ^ (d >> 3)) & 7) << 3) + (row & 7)] = pw[e];
        }
      }
      __syncthreads();
      if (kb + 1 < nkb) {
#pragma unroll
        for (int i = 0; i < 4; ++i) {
          int c = i * 256 + tid, row = c >> 4, ch = (c & 15) * 8;
          kreg[i] = *(const uint4*)(Kg + (size_t)((kb + 1) * 64 + row) * 6144 + ch);
          vreg[i] = *(const uint4*)(Vg + (size_t)((kb + 1) * 64 + row) * 6144 + ch);
        }
      }

      f32x4 st[4] = {};
#pragma unroll
      for (int kc = 0; kc < 4; ++kc)
#pragma unroll
        for (int j = 0; j < 4; ++j) {
          bf16x8 bb = *(const bf16x8*)(sK + (j * 16 + l16) * LK + kc * 32 + quad * 8);
          st[j] = __builtin_amdgcn_mfma_f32_16x16x32_bf16(bb, qa[kc], st[j], 0, 0, 0);
        }

      const int kg0 = kb * 64 + quad * 4;
      float mloc = NEGBIG;
#pragma unroll
      for (int j = 0; j < 4; ++j)
#pragma unroll
        for (int r = 0; r < 4; ++r) {
          float v = st[j][r];
          if (kg0 + j * 16 + r > qg) v = NEGBIG;
          st[j][r] = v;
          mloc = fmaxf(mloc, v);
        }
      mloc = fmaxf(mloc, __shfl_xor(mloc, 16, 64));
      mloc = fmaxf(mloc, __shfl_xor(mloc, 32, 64));

      if (__any(mloc - m_run > 8.0f)) {
        float mn = fmaxf(m_run, mloc);
        float alpha = exp2f(m_run - mn);
        m_run = mn;
        l_run *= alpha;
        float ar[4];
#pragma unroll
        for (int r = 0; r < 4; ++r) ar[r] = __shfl(alpha, quad * 4 + r, 64);
#pragma unroll
        for (int dt = 0; dt < 8; ++dt)
#pragma unroll
          for (int r = 0; r < 4; ++r) oacc[dt][r] *= ar[r];
      }

      float lad = 0.f;
#pragma unroll
      for (int j = 0; j < 4; ++j)
#pragma unroll
        for (int r = 0; r < 4; ++r) {
          float p = exp2f(st[j][r] - m_run);
          st[j][r] = p;
          lad += p;
        }
      lad += __shfl_xor(lad, 16, 64);
      lad += __shfl_xor(lad, 32, 64);
      l_run += lad;

#pragma unroll
      for (int j = 0; j < 4; ++j)
#pragma unroll
        for (int r = 0; r < 4; ++r)
          sP[(wave * 16 + l16) * LP + j * 16 + quad * 4 + r] = f2bf(st[j][r]);
      __asm__ __volatile__("s_waitcnt lgkmcnt(0)" ::: "memory");

#pragma unroll
      for (int kc = 0; kc < 2; ++kc) {
        bf16x8 a = *(const bf16x8*)(sP + (wave * 16 + l16) * LP + kc * 32 + quad * 8);
#pragma unroll
        for (int dt = 0; dt < 8; ++dt) {
          int d = dt * 16 + l16;
          int chk = ((kc * 4 + quad) ^ (d >> 3)) & 7;
          bf16x8 bb = *(const bf16x8*)(sV + d * 64 + chk * 8);
          oacc[dt] = __builtin_amdgcn_mfma_f32_16x16x32_bf16(a, bb, oacc[dt], 0, 0, 0);
        }
      }
      __syncthreads();
    }

    float lfin[4];
#pragma unroll
    for (int r = 0; r < 4; ++r) lfin[r] = __shfl(l_run, quad * 4 + r, 64);

    const int srow = qt * 64 + wave * 16 + quad * 4;
#pragma unroll
    for (int dt = 0; dt < 8; ++dt)
#pragma unroll
      for (int r = 0; r < 4; ++r) {
        float val = oacc[dt][r] / lfin[r];
        O[((size_t)b * 1024 + srow + r) * 4096 + h * 128 + dt * 16 + l16] = f2bf(val);
      }
  }
}

// ---------------------------------------------------------------------------
extern "C" void kernel_launch(void* const* d_in, const int* in_sizes, int n_in,
                              void* d_out, int out_size, void* d_ws, size_t ws_size,
                              hipStream_t stream) {
  (void)in_sizes; (void)n_in; (void)out_size; (void)ws_size;
  const void* hidden = d_in[0];  // (2048, 4096)
  const void* cosb   = d_in[1];  // (2, 1024, 128)
  const void* sinb   = d_in[2];
  // d_in[3] = attention_mask (causal; reproduced analytically)
  const void* Wq = d_in[4];  // (4096, 4096)
  const void* Wk = d_in[5];  // (4096, 1024)
  const void* Wv = d_in[6];  // (4096, 1024)
  const void* Wo = d_in[7];  // (4096, 4096)

  u16* ws = (u16*)d_ws;
  u16* Wqkvt = ws;                        // bf16 (6144,4096); reused as Wot
  u16* Wot   = ws;
  u16* Xb    = ws + (size_t)25165824;     // bf16 (2048,4096); reused as attnb
  u16* attnb = Xb;
  u16* QKV   = ws + (size_t)33554432;     // bf16 (2048,6144)
  int* flags = (int*)(ws + (size_t)46137344);  // 8 ints

  // flags: 0=hidden 1=cos 2=Wq 3=Wk 4=Wv 5=Wo, 6=always-0 (bf16 out)
  detect_dtype<<<6, 64, 0, stream>>>(hidden, cosb, Wq, Wk, Wv, Wo, flags);

  transpose_qkv<<<dim3(96, 64), 256, 0, stream>>>(Wq, Wk, Wv, Wqkvt, flags);
  cast_to_bf16<<<4096, 256, 0, stream>>>(hidden, Xb, flags + 0);

  // QKV projection: M=2048, N=6144, K=4096. 256x256 tile, 2x4 waves.
  gemm_ph<256, 256, 2, 4><<<dim3(24, 8), 512, 0, stream>>>(
      Xb, Wqkvt, QKV, 4096, 4096, 4096, 6144, flags + 6);
  rope_kernel<<<2560, 256, 0, stream>>>(QKV, cosb, sinb, flags + 1);

  // Wqkvt consumed by gemm1 -> overwrite with Wo^T (stream-ordered)
  transpose_to_bf16<<<dim3(64, 64), 256, 0, stream>>>(Wo, Wot, 4096, 4096, flags + 5);

  attn_kernel<<<dim3(8, 32, 2), 256, 0, stream>>>(QKV, attnb);

  // output projection: M=2048, N=4096, K=4096. 256x128 tile, 4x2 waves
  // -> 256 blocks = exact full-chip fill.
  gemm_ph<256, 128, 4, 2><<<dim3(32, 8), 512, 0, stream>>>(
      attnb, Wot, d_out, 4096, 4096, 4096, 4096, flags + 0);
}

// Round 4
// 471.096 us; speedup vs baseline: 1.0737x; 1.0737x over previous
//
#include <hip/hip_runtime.h>

typedef unsigned short u16;
typedef __bf16 bf16x8 __attribute__((ext_vector_type(8)));
typedef float f32x4 __attribute__((ext_vector_type(4)));

#define SCALE_QK 0.08838834764831845f
#define LOG2E 1.4426950408889634f
#define NEGBIG (-1e9f)

static __device__ __forceinline__ float bf2f(u16 u) {
  union { float f; unsigned int i; } x; x.i = ((unsigned int)u) << 16; return x.f;
}
static __device__ __forceinline__ u16 f2bf(float f) {
  union { float f; unsigned int i; } x; x.f = f;
  return (u16)((x.i + 0x7fffu + ((x.i >> 16) & 1u)) >> 16);
}
static __device__ __forceinline__ void async16(const u16* g, u16* s) {
  __builtin_amdgcn_global_load_lds(
      (const __attribute__((address_space(1))) void*)g,
      (__attribute__((address_space(3))) void*)s, 16, 0, 0);
}

// -------- dtype probe: flags[t]=1 if tensor t is f32-stored, 0 if bf16 ------
__global__ __launch_bounds__(64) void detect_dtype(
    const void* p0, const void* p1, const void* p2, const void* p3,
    const void* p4, const void* p5, int* flags) {
  const void* ps[6] = {p0, p1, p2, p3, p4, p5};
  const u16* p = (const u16*)ps[blockIdx.x];
  int lane = threadIdx.x;
  u16 u = p[2 * lane];
  int e = (u >> 7) & 0xFF;
  int plaus = (e >= 112 && e <= 143) ? 1 : 0;
  unsigned long long m = __ballot(plaus);
  if (lane == 0) {
    flags[blockIdx.x] = (__popcll(m) < 32) ? 1 : 0;
    if (blockIdx.x == 0) flags[6] = 0;  // forced-bf16 flag (internal GEMM out)
  }
}

// -------- shared transpose body: src (K x N) tile -> dst bf16 (N x K) -------
static __device__ __forceinline__ void transpose_body(
    const void* __restrict__ src, u16* __restrict__ dst, int N, int K,
    int n0, int k0, int f32in, u16* t) {
  const int LT = 74;
  const int tid = threadIdx.x;
  for (int c = tid; c < 512; c += 256) {
    int r = c >> 3, ch = (c & 7) * 8;
    u16* tp = t + r * LT + ch;
    if (f32in) {
      const float* p = (const float*)src + (size_t)(k0 + r) * N + n0 + ch;
      float4 v0 = *(const float4*)p;
      float4 v1 = *(const float4*)(p + 4);
      tp[0] = f2bf(v0.x); tp[1] = f2bf(v0.y); tp[2] = f2bf(v0.z); tp[3] = f2bf(v0.w);
      tp[4] = f2bf(v1.x); tp[5] = f2bf(v1.y); tp[6] = f2bf(v1.z); tp[7] = f2bf(v1.w);
    } else {
      uint4 v = *(const uint4*)((const u16*)src + (size_t)(k0 + r) * N + n0 + ch);
      const u16* pv = (const u16*)&v;
#pragma unroll
      for (int e = 0; e < 8; ++e) tp[e] = pv[e];
    }
  }
  __syncthreads();
  for (int c = tid; c < 512; c += 256) {
    int rr = c >> 3, cc = (c & 7) * 8;
    u16 tmp[8];
#pragma unroll
    for (int e = 0; e < 8; ++e) tmp[e] = t[(cc + e) * LT + rr];
    *(uint4*)(dst + (size_t)(n0 + rr) * K + k0 + cc) = *(const uint4*)tmp;
  }
}

// -------- transpose: generic single-tensor version (used for Wo) ------------
__global__ __launch_bounds__(256) void transpose_to_bf16(
    const void* __restrict__ src, u16* __restrict__ dst, int N, int K,
    const int* __restrict__ flag) {
  __shared__ u16 t[64 * 74];
  transpose_body(src, dst, N, K, blockIdx.x * 64, blockIdx.y * 64, *flag, t);
}

// -------- fused: transpose Wq/Wk/Wv + cast hidden (one launch) --------------
// bx 0..63: Wq tiles; 64..79: Wk; 80..95: Wv; 96..159: cast hidden blocks.
__global__ __launch_bounds__(256) void prep_fused(
    const void* __restrict__ Wq, const void* __restrict__ Wk,
    const void* __restrict__ Wv, u16* __restrict__ dst,
    const void* __restrict__ hidden, u16* __restrict__ Xb,
    const int* __restrict__ flags) {
  __shared__ u16 t[64 * 74];
  int bx = blockIdx.x;
  if (bx < 96) {
    const void* src; u16* d; int N; int f32in; int nx;
    if (bx < 64)      { src = Wq; d = dst;                       N = 4096; f32in = flags[2]; nx = bx; }
    else if (bx < 80) { src = Wk; d = dst + (size_t)4096 * 4096; N = 1024; f32in = flags[3]; nx = bx - 64; }
    else              { src = Wv; d = dst + (size_t)5120 * 4096; N = 1024; f32in = flags[4]; nx = bx - 80; }
    transpose_body(src, d, N, 4096, nx * 64, blockIdx.y * 64, f32in, t);
  } else {
    int i = (((bx - 96) * 64 + blockIdx.y) * 256 + threadIdx.x) * 8;
    if (flags[0]) {
      float4 v0 = *(const float4*)((const float*)hidden + i);
      float4 v1 = *(const float4*)((const float*)hidden + i + 4);
      u16 tmp[8] = {f2bf(v0.x), f2bf(v0.y), f2bf(v0.z), f2bf(v0.w),
                    f2bf(v1.x), f2bf(v1.y), f2bf(v1.z), f2bf(v1.w)};
      *(uint4*)(Xb + i) = *(const uint4*)tmp;
    } else {
      *(uint4*)(Xb + i) = *(const uint4*)((const u16*)hidden + i);
    }
  }
}

// -------- phased GEMM: C(MxN) = A(MxK)*Bt(NxK)^T ---------------------------
// 4-deep half-K-tile (BK=32) circular pipeline with COUNTED vmcnt (T4):
//  - LDS: 4 stages of (BM*32 A + BN*32 B) elems. Stage s = half h & 3.
//  - iter h: {ds_read frags from stage h&3} {issue stage h+3 (L gload_lds)}
//    {lgkmcnt(0); sched_barrier} {setprio1; FM*FN MFMA; setprio0}
//    {vmcnt(2L) steady / L / 0 tail} {s_barrier}.
//  - steady-state vmcnt(2L): half h+1's loads were issued 2 iterations ago
//    (~2500 cyc flight) -> wait is free; loads NEVER drained mid-loop.
//  - hazard: stage(h+3) overwrites buf holding half h-1; all reads of h-1
//    finished at lgkmcnt(0) before the end-of-(h-1) barrier, which precedes
//    this iter's stage issue. Stage writes awaited by vmcnt+barrier @ h+2.
//  - T2 swizzle (both sides, rule 21): involution chunk ^= (row>>1)&3 on 16B
//    chunks within each 64B LDS row; applied on the per-lane GLOBAL source
//    (LDS dest stays linear for gload_lds) and on the ds_read address.
//    Spreads the 16-row frag read across 8 bank-groups at 2-way (free).
//  - T1: XCD owns CONTIGUOUS bn column panels (B panel L2-resident; A shared
//    across XCDs via L3). Grids are multiples of 8.
template <int BM, int BN, int NWM, int NWN>
__global__ __launch_bounds__(512, 2) void gemm_ph(
    const u16* __restrict__ A, const u16* __restrict__ Bt, void* __restrict__ C,
    int K, int lda, int ldb, int ldc, const int* __restrict__ oflag) {
  constexpr int AL = BM / 128, BL = BN / 128, L = AL + BL;  // loads/thread/half
  constexpr int HALF = (BM + BN) * 32;                      // elems per stage
  constexpr int WM = BM / NWM, WN = BN / NWN;
  constexpr int FM = WM / 16, FN = WN / 16;
  __shared__ u16 lds[HALF * 4];
  const int tid = threadIdx.x;
  const int wave = tid >> 6, lane = tid & 63;
  const int quad = lane >> 4, l16 = lane & 15;
  const int wr = wave / NWN, wc = wave % NWN;

  const int nwg = gridDim.x * gridDim.y;
  const int flat = blockIdx.y * gridDim.x + blockIdx.x;
  const int swz = (flat & 7) * (nwg >> 3) + (flat >> 3);
  const int bm = (swz % gridDim.y) * BM;  // col-major: XCD = contiguous bn
  const int bn = (swz / gridDim.y) * BN;
  const int f32out = *oflag;

  // stage-source precompute (global side of the chunk-XOR involution)
  int rA[AL], kA[AL], rB[BL], kB[BL];
#pragma unroll
  for (int i = 0; i < AL; ++i) {
    int c = i * 512 + tid; rA[i] = c >> 2;
    kA[i] = ((c & 3) ^ ((rA[i] >> 1) & 3)) * 8;
  }
#pragma unroll
  for (int i = 0; i < BL; ++i) {
    int c = i * 512 + tid; rB[i] = c >> 2;
    kB[i] = ((c & 3) ^ ((rB[i] >> 1) & 3)) * 8;
  }
  const int H = K >> 5;  // # half-K-tiles

  // ds_read chunk offset (elems), same involution (row parity pair = l16>>1)
  const int ch = (quad ^ ((l16 >> 1) & 3)) * 8;

  auto STAGE = [&](int hh) {
    u16* dst = lds + (hh & 3) * HALF;
#pragma unroll
    for (int i = 0; i < AL; ++i)
      async16(A + (size_t)(bm + rA[i]) * lda + hh * 32 + kA[i],
              dst + (i * 512 + tid) * 8);
#pragma unroll
    for (int i = 0; i < BL; ++i)
      async16(Bt + (size_t)(bn + rB[i]) * ldb + hh * 32 + kB[i],
              dst + BM * 32 + (i * 512 + tid) * 8);
  };

  f32x4 acc[FM][FN] = {};

  STAGE(0); STAGE(1); STAGE(2);
  if constexpr (L == 4) { asm volatile("s_waitcnt vmcnt(8)" ::: "memory"); }
  else                  { asm volatile("s_waitcnt vmcnt(6)" ::: "memory"); }
  asm volatile("s_barrier" ::: "memory");

  for (int hh = 0; hh < H; ++hh) {
    const u16* bufA = lds + (hh & 3) * HALF;
    const u16* bufB = bufA + BM * 32;
    bf16x8 af[FM], bv[FN];
#pragma unroll
    for (int mi = 0; mi < FM; ++mi)
      af[mi] = *(const bf16x8*)(bufA + (wr * WM + mi * 16 + l16) * 32 + ch);
#pragma unroll
    for (int ni = 0; ni < FN; ++ni)
      bv[ni] = *(const bf16x8*)(bufB + (wc * WN + ni * 16 + l16) * 32 + ch);
    if (hh + 3 < H) STAGE(hh + 3);
    asm volatile("s_waitcnt lgkmcnt(0)" ::: "memory");
    __builtin_amdgcn_sched_barrier(0);
    __builtin_amdgcn_s_setprio(1);
#pragma unroll
    for (int mi = 0; mi < FM; ++mi)
#pragma unroll
      for (int ni = 0; ni < FN; ++ni)
        acc[mi][ni] = __builtin_amdgcn_mfma_f32_16x16x32_bf16(
            af[mi], bv[ni], acc[mi][ni], 0, 0, 0);
    __builtin_amdgcn_s_setprio(0);
    // counted wait: half hh+1 must be resident; allow {hh+2, hh+3} in flight
    if (hh + 3 < H) {
      if constexpr (L == 4) { asm volatile("s_waitcnt vmcnt(8)" ::: "memory"); }
      else                  { asm volatile("s_waitcnt vmcnt(6)" ::: "memory"); }
    } else if (hh + 2 < H) {
      if constexpr (L == 4) { asm volatile("s_waitcnt vmcnt(4)" ::: "memory"); }
      else                  { asm volatile("s_waitcnt vmcnt(3)" ::: "memory"); }
    } else if (hh + 1 < H) {
      asm volatile("s_waitcnt vmcnt(0)" ::: "memory");
    }
    asm volatile("s_barrier" ::: "memory");
  }

  // epilogue (C/D layout: row = m*16 + quad*4 + r, col = n*16 + l16)
#pragma unroll
  for (int mi = 0; mi < FM; ++mi) {
    int row = bm + wr * WM + mi * 16 + quad * 4;
#pragma unroll
    for (int ni = 0; ni < FN; ++ni) {
      int col = bn + wc * WN + ni * 16 + l16;
#pragma unroll
      for (int r = 0; r < 4; ++r) {
        size_t idx = (size_t)(row + r) * ldc + col;
        if (f32out) ((float*)C)[idx] = acc[mi][ni][r];
        else ((u16*)C)[idx] = f2bf(acc[mi][ni][r]);
      }
    }
  }
}

// -------- RoPE in place, vectorized x8: Q (slots 0..31), K (slots 32..39) ---
__global__ __launch_bounds__(256) void rope_kernel(
    u16* __restrict__ QKV, const void* __restrict__ cosb,
    const void* __restrict__ sinb, const int* __restrict__ flag) {
  int idx = blockIdx.x * 256 + threadIdx.x;  // (tok*40 + slot)*8 + d-octet
  int d8 = (idx & 7) * 8;
  int rest = idx >> 3;
  int slot = rest % 40;
  int tok = rest / 40;
  int col = (slot < 32) ? (slot * 128 + d8) : (4096 + (slot - 32) * 128 + d8);
  size_t base = (size_t)tok * 6144 + col;
  uint4 va = *(const uint4*)(QKV + base);
  uint4 vb = *(const uint4*)(QKV + base + 64);
  const u16* pa = (const u16*)&va;
  const u16* pb = (const u16*)&vb;
  size_t cb = (size_t)tok * 128 + d8;
  float c1[8], s1[8], c2[8], s2[8];
  if (*flag) {
    const float* cp = (const float*)cosb + cb;
    const float* sp = (const float*)sinb + cb;
    float4 t0 = *(const float4*)cp,        t1 = *(const float4*)(cp + 4);
    float4 t2 = *(const float4*)(cp + 64), t3 = *(const float4*)(cp + 68);
    float4 u0 = *(const float4*)sp,        u1 = *(const float4*)(sp + 4);
    float4 u2 = *(const float4*)(sp + 64), u3 = *(const float4*)(sp + 68);
    c1[0]=t0.x;c1[1]=t0.y;c1[2]=t0.z;c1[3]=t0.w;c1[4]=t1.x;c1[5]=t1.y;c1[6]=t1.z;c1[7]=t1.w;
    c2[0]=t2.x;c2[1]=t2.y;c2[2]=t2.z;c2[3]=t2.w;c2[4]=t3.x;c2[5]=t3.y;c2[6]=t3.z;c2[7]=t3.w;
    s1[0]=u0.x;s1[1]=u0.y;s1[2]=u0.z;s1[3]=u0.w;s1[4]=u1.x;s1[5]=u1.y;s1[6]=u1.z;s1[7]=u1.w;
    s2[0]=u2.x;s2[1]=u2.y;s2[2]=u2.z;s2[3]=u2.w;s2[4]=u3.x;s2[5]=u3.y;s2[6]=u3.z;s2[7]=u3.w;
  } else {
    const u16* cp = (const u16*)cosb + cb;
    const u16* sp = (const u16*)sinb + cb;
    uint4 t0 = *(const uint4*)cp, t1 = *(const uint4*)(cp + 64);
    uint4 u0 = *(const uint4*)sp, u1 = *(const uint4*)(sp + 64);
    const u16* q0 = (const u16*)&t0; const u16* q1 = (const u16*)&t1;
    const u16* r0 = (const u16*)&u0; const u16* r1 = (const u16*)&u1;
#pragma unroll
    for (int e = 0; e < 8; ++e) {
      c1[e] = bf2f(q0[e]); c2[e] = bf2f(q1[e]);
      s1[e] = bf2f(r0[e]); s2[e] = bf2f(r1[e]);
    }
  }
  u16 o1[8], o2[8];
#pragma unroll
  for (int e = 0; e < 8; ++e) {
    float x1 = bf2f(pa[e]), x2 = bf2f(pb[e]);
    o1[e] = f2bf(x1 * c1[e] - x2 * s1[e]);
    o2[e] = f2bf(x2 * c2[e] + x1 * s2[e]);
  }
  *(uint4*)(QKV + base) = *(const uint4*)o1;
  *(uint4*)(QKV + base + 64) = *(const uint4*)o2;
}

// -------- flash attention: BQ=BKV=64, causal, GQA 4:1 -----------------------
// Swapped QK^T (mfma(K,Q) -> S^T), per-lane in-register softmax, defer-max
// (THR=8, log2 domain), sP transposed round-trip, sV XOR-swizzled
// transpose-store, K/V next-tile reg prefetch, paired q-tiles {p,15-p}.
__global__ __launch_bounds__(256, 3) void attn_kernel(
    const u16* __restrict__ QKV, u16* __restrict__ O) {
  const int LK = 136;
  const int LP = 72;
  __shared__ u16 sK[64 * LK];
  __shared__ u16 sV[128 * 64];
  __shared__ u16 sP[64 * LP];
  const int tid = threadIdx.x, wave = tid >> 6, lane = tid & 63;
  const int quad = lane >> 4, l16 = lane & 15;
  const int pp = blockIdx.x, h = blockIdx.y, b = blockIdx.z;
  const int kvh = h >> 2;
  const size_t tb = (size_t)b * 1024 * 6144;
  const u16* Qg = QKV + tb + (size_t)h * 128;
  const u16* Kg = QKV + tb + 4096 + (size_t)kvh * 128;
  const u16* Vg = QKV + tb + 5120 + (size_t)kvh * 128;

#pragma unroll 1
  for (int pass = 0; pass < 2; ++pass) {
    const int qt = pass ? (15 - pp) : pp;

    bf16x8 qa[4];
    {
      const int qrow = qt * 64 + wave * 16 + l16;
#pragma unroll
      for (int kc = 0; kc < 4; ++kc) {
        bf16x8 v = *(const bf16x8*)(Qg + (size_t)qrow * 6144 + kc * 32 + quad * 8);
#pragma unroll
        for (int e = 0; e < 8; ++e) v[e] = (__bf16)((float)v[e] * (SCALE_QK * LOG2E));
        qa[kc] = v;
      }
    }

    uint4 kreg[4], vreg[4];
#pragma unroll
    for (int i = 0; i < 4; ++i) {
      int c = i * 256 + tid, row = c >> 4, ch = (c & 15) * 8;
      kreg[i] = *(const uint4*)(Kg + (size_t)row * 6144 + ch);
      vreg[i] = *(const uint4*)(Vg + (size_t)row * 6144 + ch);
    }

    float m_run = -INFINITY, l_run = 0.f;
    f32x4 oacc[8] = {};
    const int qg = qt * 64 + wave * 16 + l16;

    const int nkb = qt + 1;
    for (int kb = 0; kb < nkb; ++kb) {
#pragma unroll
      for (int i = 0; i < 4; ++i) {
        int c = i * 256 + tid, row = c >> 4, ch = (c & 15) * 8;
        *(uint4*)(sK + row * LK + ch) = kreg[i];
        const u16* pw = (const u16*)&vreg[i];
#pragma unroll
        for (int e = 0; e < 8; ++e) {
          int d = ch + e;
          sV[d * 64 + ((((row >> 3) ^ (d >> 3)) & 7) << 3) + (row & 7)] = pw[e];
        }
      }
      __syncthreads();
      if (kb + 1 < nkb) {
#pragma unroll
        for (int i = 0; i < 4; ++i) {
          int c = i * 256 + tid, row = c >> 4, ch = (c & 15) * 8;
          kreg[i] = *(const uint4*)(Kg + (size_t)((kb + 1) * 64 + row) * 6144 + ch);
          vreg[i] = *(const uint4*)(Vg + (size_t)((kb + 1) * 64 + row) * 6144 + ch);
        }
      }

      f32x4 st[4] = {};
#pragma unroll
      for (int kc = 0; kc < 4; ++kc)
#pragma unroll
        for (int j = 0; j < 4; ++j) {
          bf16x8 bb = *(const bf16x8*)(sK + (j * 16 + l16) * LK + kc * 32 + quad * 8);
          st[j] = __builtin_amdgcn_mfma_f32_16x16x32_bf16(bb, qa[kc], st[j], 0, 0, 0);
        }

      const int kg0 = kb * 64 + quad * 4;
      float mloc = NEGBIG;
#pragma unroll
      for (int j = 0; j < 4; ++j)
#pragma unroll
        for (int r = 0; r < 4; ++r) {
          float v = st[j][r];
          if (kg0 + j * 16 + r > qg) v = NEGBIG;
          st[j][r] = v;
          mloc = fmaxf(mloc, v);
        }
      mloc = fmaxf(mloc, __shfl_xor(mloc, 16, 64));
      mloc = fmaxf(mloc, __shfl_xor(mloc, 32, 64));

      if (__any(mloc - m_run > 8.0f)) {
        float mn = fmaxf(m_run, mloc);
        float alpha = exp2f(m_run - mn);
        m_run = mn;
        l_run *= alpha;
        float ar[4];
#pragma unroll
        for (int r = 0; r < 4; ++r) ar[r] = __shfl(alpha, quad * 4 + r, 64);
#pragma unroll
        for (int dt = 0; dt < 8; ++dt)
#pragma unroll
          for (int r = 0; r < 4; ++r) oacc[dt][r] *= ar[r];
      }

      float lad = 0.f;
#pragma unroll
      for (int j = 0; j < 4; ++j)
#pragma unroll
        for (int r = 0; r < 4; ++r) {
          float p = exp2f(st[j][r] - m_run);
          st[j][r] = p;
          lad += p;
        }
      lad += __shfl_xor(lad, 16, 64);
      lad += __shfl_xor(lad, 32, 64);
      l_run += lad;

#pragma unroll
      for (int j = 0; j < 4; ++j)
#pragma unroll
        for (int r = 0; r < 4; ++r)
          sP[(wave * 16 + l16) * LP + j * 16 + quad * 4 + r] = f2bf(st[j][r]);
      __asm__ __volatile__("s_waitcnt lgkmcnt(0)" ::: "memory");

#pragma unroll
      for (int kc = 0; kc < 2; ++kc) {
        bf16x8 a = *(const bf16x8*)(sP + (wave * 16 + l16) * LP + kc * 32 + quad * 8);
#pragma unroll
        for (int dt = 0; dt < 8; ++dt) {
          int d = dt * 16 + l16;
          int chk = ((kc * 4 + quad) ^ (d >> 3)) & 7;
          bf16x8 bb = *(const bf16x8*)(sV + d * 64 + chk * 8);
          oacc[dt] = __builtin_amdgcn_mfma_f32_16x16x32_bf16(a, bb, oacc[dt], 0, 0, 0);
        }
      }
      __syncthreads();
    }

    float lfin[4];
#pragma unroll
    for (int r = 0; r < 4; ++r) lfin[r] = __shfl(l_run, quad * 4 + r, 64);

    const int srow = qt * 64 + wave * 16 + quad * 4;
#pragma unroll
    for (int dt = 0; dt < 8; ++dt)
#pragma unroll
      for (int r = 0; r < 4; ++r) {
        float val = oacc[dt][r] / lfin[r];
        O[((size_t)b * 1024 + srow + r) * 4096 + h * 128 + dt * 16 + l16] = f2bf(val);
      }
  }
}

// ---------------------------------------------------------------------------
extern "C" void kernel_launch(void* const* d_in, const int* in_sizes, int n_in,
                              void* d_out, int out_size, void* d_ws, size_t ws_size,
                              hipStream_t stream) {
  (void)in_sizes; (void)n_in; (void)out_size; (void)ws_size;
  const void* hidden = d_in[0];  // (2048, 4096)
  const void* cosb   = d_in[1];  // (2, 1024, 128)
  const void* sinb   = d_in[2];
  // d_in[3] = attention_mask (causal; reproduced analytically)
  const void* Wq = d_in[4];  // (4096, 4096)
  const void* Wk = d_in[5];  // (4096, 1024)
  const void* Wv = d_in[6];  // (4096, 1024)
  const void* Wo = d_in[7];  // (4096, 4096)

  u16* ws = (u16*)d_ws;
  u16* Wqkvt = ws;                        // bf16 (6144,4096); reused as Wot
  u16* Wot   = ws;
  u16* Xb    = ws + (size_t)25165824;     // bf16 (2048,4096); reused as attnb
  u16* attnb = Xb;
  u16* QKV   = ws + (size_t)33554432;     // bf16 (2048,6144)
  int* flags = (int*)(ws + (size_t)46137344);  // 8 ints

  // flags: 0=hidden 1=cos 2=Wq 3=Wk 4=Wv 5=Wo, 6=always-0 (bf16 out)
  detect_dtype<<<6, 64, 0, stream>>>(hidden, cosb, Wq, Wk, Wv, Wo, flags);

  // fused: Wq/Wk/Wv transpose + hidden cast (one launch)
  prep_fused<<<dim3(160, 64), 256, 0, stream>>>(Wq, Wk, Wv, Wqkvt, hidden, Xb, flags);

  // QKV projection: M=2048, N=6144, K=4096. 256x256 tile, 2x4 waves, 192 wg.
  gemm_ph<256, 256, 2, 4><<<dim3(24, 8), 512, 0, stream>>>(
      Xb, Wqkvt, QKV, 4096, 4096, 4096, 6144, flags + 6);
  rope_kernel<<<2560, 256, 0, stream>>>(QKV, cosb, sinb, flags + 1);

  // Wqkvt consumed by gemm1 -> overwrite with Wo^T (stream-ordered)
  transpose_to_bf16<<<dim3(64, 64), 256, 0, stream>>>(Wo, Wot, 4096, 4096, flags + 5);

  attn_kernel<<<dim3(8, 32, 2), 256, 0, stream>>>(QKV, attnb);

  // output projection: M=2048, N=4096, K=4096. 256x128 tile, 4x2 waves,
  // 256 wg = exact full-chip fill.
  gemm_ph<256, 128, 4, 2><<<dim3(32, 8), 512, 0, stream>>>(
      attnb, Wot, d_out, 4096, 4096, 4096, 4096, flags + 0);
}